// Round 9
// baseline (2796.929 us; speedup 1.0000x reference)
//
#include <hip/hip_runtime.h>

#define N_PTS 8192
#define M_PTS 2048
#define K_NN 16
#define IN_CH 64
#define G_CH 68
#define OUT_CH 128
#define KCAP 128

// Unfusable fp32 ops: inline asm cannot be FMA-contracted by the compiler.
__device__ __forceinline__ float subrn(float a, float b) {
    float r; asm("v_sub_f32 %0, %1, %2" : "=v"(r) : "v"(a), "v"(b)); return r;
}
__device__ __forceinline__ float mulrn(float a, float b) {
    float r; asm("v_mul_f32 %0, %1, %2" : "=v"(r) : "v"(a), "v"(b)); return r;
}
__device__ __forceinline__ float addrn(float a, float b) {
    float r; asm("v_add_f32 %0, %1, %2" : "=v"(r) : "v"(a), "v"(b)); return r;
}
// numpy-exact fp32 squared distance: ((dx*dx + dy*dy) + dz*dz), per-op rounding.
__device__ __forceinline__ float sqdist_rn(float ax, float ay, float az,
                                           float bx, float by, float bz) {
    float dx = subrn(ax, bx);
    float dy = subrn(ay, by);
    float dz = subrn(az, bz);
    return addrn(addrn(mulrn(dx, dx), mulrn(dy, dy)), mulrn(dz, dz));
}

// Packed 2xfp32 ops (VOP3P). Each half is a plain IEEE fp32 op -> numerics
// bit-identical to scalar. Subtraction as a + (-b) (exact sign flip).
typedef float v2f __attribute__((ext_vector_type(2)));
__device__ __forceinline__ v2f pk_add(v2f a, v2f b) {
    v2f r; asm("v_pk_add_f32 %0, %1, %2" : "=v"(r) : "v"(a), "v"(b)); return r;
}
__device__ __forceinline__ v2f pk_mul(v2f a, v2f b) {
    v2f r; asm("v_pk_mul_f32 %0, %1, %2" : "=v"(r) : "v"(a), "v"(b)); return r;
}

// ---- DPP helpers ----------------------------------------------------------
template <int CTRL>
__device__ __forceinline__ float movdpp_f(float x) {
    int r = __builtin_amdgcn_mov_dpp(__float_as_int(x), CTRL, 0xf, 0xf, true);
    return __int_as_float(r);
}
// masked bcast stages for wave max: update_dpp old=0 (max with 0 safe, d>=0)
template <int CTRL, int RM>
__device__ __forceinline__ float dppmaxf_m(float x) {
    int r = __builtin_amdgcn_update_dpp(0, __float_as_int(x), CTRL, RM, 0xf, false);
    return fmaxf(x, __int_as_float(r));
}
// full 64-lane max -> valid in lane 63
__device__ __forceinline__ float wave_max64(float x) {
    x = fmaxf(x, movdpp_f<0xB1>(x));   // quad_perm xor1
    x = fmaxf(x, movdpp_f<0x4E>(x));   // quad_perm xor2
    x = fmaxf(x, movdpp_f<0x141>(x));  // row_half_mirror
    x = fmaxf(x, movdpp_f<0x140>(x));  // row_mirror
    x = dppmaxf_m<0x142, 0xa>(x);      // row_bcast15 -> rows 1,3
    x = dppmaxf_m<0x143, 0xc>(x);      // row_bcast31 -> lane63 full
    return x;
}
// 4-lane-group max (lane%4-aligned)
__device__ __forceinline__ float group4_max(float x) {
    x = fmaxf(x, movdpp_f<0xB1>(x));
    x = fmaxf(x, movdpp_f<0x4E>(x));
    return x;
}
// 8-lane-group max (lane%8-aligned) -- used by knn
__device__ __forceinline__ float group8_max(float x) {
    x = fmaxf(x, movdpp_f<0xB1>(x));
    x = fmaxf(x, movdpp_f<0x4E>(x));
    x = fmaxf(x, movdpp_f<0x141>(x));
    return x;
}

// ---------------------------------------------------------------------------
// Kernel 1: FPS, one block (256 thr, 4 waves) per batch. Bit-exact fp32
// (no FMA) distance chain. Thread t owns interleaved points {j*256+t}.
// Winner published via LDS atomicMin on the GLOBAL point index (smallest
// index wins on exact ties == np argmax first-occurrence, layout-agnostic).
// Double-buffered winner slot; 2 barriers/iter with 4-wave cost.
// ---------------------------------------------------------------------------
__global__ __launch_bounds__(256) void fps_kernel(const float4* __restrict__ events4,
                                                  int* __restrict__ down_idx,
                                                  float4* __restrict__ out_de) {
    extern __shared__ char smem[];
    float*  rv   = (float*)smem;                   // 4 floats: wave-max partials
    int*    wsl  = (int*)(smem + 16);              // 2 ints: winner (double-buffer)
    int*    ssel = (int*)(smem + 32);              // 2048 ints
    float4* spt  = (float4*)(smem + 32 + 4 * M_PTS);

    const int b = blockIdx.x;
    const int tid = threadIdx.x;
    const int wave = tid >> 6;
    const int lane = tid & 63;
    const float4* ev = events4 + (size_t)b * N_PTS;

    for (int i = tid; i < N_PTS; i += 256) spt[i] = ev[i];
    if (tid == 0) { ssel[0] = 0; wsl[0] = 0x7fffffff; wsl[1] = 0x7fffffff; }
    __syncthreads();

    // 32 pts/thread, interleaved (conflict-free init), packed in pairs:
    // pair pp holds points (2pp)*256+tid and (2pp+1)*256+tid
    v2f px[16], py[16], pz[16];
    float dist[32];
#pragma unroll
    for (int pp = 0; pp < 16; ++pp) {
        float4 f0 = spt[(2 * pp) * 256 + tid];
        float4 f1 = spt[(2 * pp + 1) * 256 + tid];
        px[pp] = (v2f){f0.x, f1.x};
        py[pp] = (v2f){f0.y, f1.y};
        pz[pp] = (v2f){f0.z, f1.z};
        dist[2 * pp] = 1e10f; dist[2 * pp + 1] = 1e10f;   // reference init
    }

    int last = 0;
    for (int i = 1; i < M_PTS; ++i) {
        float4 L = spt[last];                     // uniform ds_read_b128
        const float nlx = -L.x, nly = -L.y, nlz = -L.z;   // exact sign flips
        const v2f nx2 = (v2f){nlx, nlx};
        const v2f ny2 = (v2f){nly, nly};
        const v2f nz2 = (v2f){nlz, nlz};
#pragma unroll
        for (int pp = 0; pp < 16; ++pp) {
            v2f dx = pk_add(px[pp], nx2);         // == px - lx, exact
            v2f dy = pk_add(py[pp], ny2);
            v2f dz = pk_add(pz[pp], nz2);
            v2f s  = pk_add(pk_add(pk_mul(dx, dx), pk_mul(dy, dy)), pk_mul(dz, dz));
            dist[2 * pp]     = fminf(dist[2 * pp],     s.x);
            dist[2 * pp + 1] = fminf(dist[2 * pp + 1], s.y);
        }
        // fmax tree over 32 dists
        float t0[16];
#pragma unroll
        for (int j = 0; j < 16; ++j) t0[j] = fmaxf(dist[2 * j], dist[2 * j + 1]);
#pragma unroll
        for (int j = 0; j < 8; ++j) t0[j] = fmaxf(t0[2 * j], t0[2 * j + 1]);
#pragma unroll
        for (int j = 0; j < 4; ++j) t0[j] = fmaxf(t0[2 * j], t0[2 * j + 1]);
        float bd = fmaxf(fmaxf(t0[0], t0[1]), fmaxf(t0[2], t0[3]));

        // block max: wave DPP reduce -> 4 LDS partials -> group4 DPP
        float wm = wave_max64(bd);
        if (lane == 63) rv[wave] = wm;
        __syncthreads();                          // B1: publish rv
        float bm = group4_max(rv[lane & 3]);      // uniform block max

        // candidates (bd == bm): resolve smallest local j, atomicMin global idx
        if (bd == bm) {
            int jm = 0;
#pragma unroll
            for (int j = 31; j >= 0; --j) if (dist[j] == bd) jm = j;
            atomicMin(&wsl[i & 1], jm * 256 + tid);   // global idx; min == np tie-break
        }
        __syncthreads();                          // B2: publish winner
        last = wsl[i & 1];
        if (tid == 0) { ssel[i] = last; wsl[(i + 1) & 1] = 0x7fffffff; }
    }
    __syncthreads();

    for (int i = tid; i < M_PTS; i += 256) {
        int s = ssel[i];
        down_idx[b * M_PTS + i] = s;
        out_de[(size_t)b * M_PTS + i] = spt[s];
    }
}

// ---------------------------------------------------------------------------
// Kernel 2: 16-NN, divergence-free threshold algorithm (unchanged from R7/R8).
// ---------------------------------------------------------------------------
__global__ __launch_bounds__(256) void knn_kernel(const float4* __restrict__ events4,
                                                  const int* __restrict__ down_idx,
                                                  int* __restrict__ knn_idx) {
    extern __shared__ char smem[];
    float* sx   = (float*)smem;
    float* sy   = sx + N_PTS;
    float* sz   = sy + N_PTS;
    float* cd   = sz + N_PTS;
    int*   ci   = (int*)(cd + 32 * KCAP);
    int*   scnt = (int*)(ci + 32 * KCAP);

    const int b    = blockIdx.x >> 6;
    const int qg   = blockIdx.x & 63;
    const int tid  = threadIdx.x;
    const int ql   = tid >> 3;
    const int part = tid & 7;

    const float4* ev = events4 + (size_t)b * N_PTS;
    for (int i = tid; i < N_PTS; i += 256) {
        float4 e = ev[i];
        sx[i] = e.x; sy[i] = e.y; sz[i] = e.z;
    }
    if (tid < 32) scnt[tid] = 0;
    __syncthreads();

    const int q  = qg * 32 + ql;
    const int qi = down_idx[b * M_PTS + q];
    const float qx = sx[qi], qy = sy[qi], qz = sz[qi];

    float m1 = 1e30f, m2 = 1e30f;
    for (int i = 0; i < N_PTS / 8; ++i) {
        const int p = i * 8 + part;
        float d = sqdist_rn(sx[p], sy[p], sz[p], qx, qy, qz);
        float lo = fminf(m1, d);
        m2 = fminf(m2, fmaxf(m1, d));
        m1 = lo;
    }
    const float T = group8_max(m2);

    for (int i = 0; i < N_PTS / 8; ++i) {
        const int p = i * 8 + part;
        float d = sqdist_rn(sx[p], sy[p], sz[p], qx, qy, qz);
        if (d <= T) {
            int pos = atomicAdd(&scnt[ql], 1);
            if (pos < KCAP) { cd[ql * KCAP + pos] = d; ci[ql * KCAP + pos] = p; }
        }
    }
    __syncthreads();

    if (part == 0) {
        float nd[16]; int ni[16];
#pragma unroll
        for (int j = 0; j < 16; ++j) { nd[j] = 1e30f; ni[j] = 0x7fffffff; }
        float wmax = 1e30f; int widx = 0x7fffffff; int wslot = 0;
        const int n = scnt[ql];
        const int lim = (n <= KCAP) ? n : 0;
        for (int t = 0; t < lim; ++t) {
            float d = cd[ql * KCAP + t];
            int   p = ci[ql * KCAP + t];
            if (d < wmax || (d == wmax && p < widx)) {
#pragma unroll
                for (int j = 0; j < 16; ++j) if (j == wslot) { nd[j] = d; ni[j] = p; }
                float m_ = -1.0f; int mix_ = -1; int ms_ = 0;
#pragma unroll
                for (int j = 0; j < 16; ++j)
                    if (nd[j] > m_ || (nd[j] == m_ && ni[j] > mix_)) { m_ = nd[j]; mix_ = ni[j]; ms_ = j; }
                wmax = m_; widx = mix_; wslot = ms_;
            }
        }
        if (n > KCAP) {
            for (int p = 0; p < N_PTS; ++p) {
                float d = sqdist_rn(sx[p], sy[p], sz[p], qx, qy, qz);
                if (d < wmax || (d == wmax && p < widx)) {
#pragma unroll
                    for (int j = 0; j < 16; ++j) if (j == wslot) { nd[j] = d; ni[j] = p; }
                    float m_ = -1.0f; int mix_ = -1; int ms_ = 0;
#pragma unroll
                    for (int j = 0; j < 16; ++j)
                        if (nd[j] > m_ || (nd[j] == m_ && ni[j] > mix_)) { m_ = nd[j]; mix_ = ni[j]; ms_ = j; }
                    wmax = m_; widx = mix_; wslot = ms_;
                }
            }
        }
        int* out = knn_idx + ((size_t)(b * M_PTS + q)) * K_NN;
#pragma unroll
        for (int j = 0; j < 16; ++j) out[j] = ni[j];
    }
}

// ---------------------------------------------------------------------------
// Kernel 3: gather + per-query (16x68)@(68x128) matmul + bias (unchanged).
// ---------------------------------------------------------------------------
__global__ __launch_bounds__(256) void gmm_kernel(const float* __restrict__ events,
                                                  const float* __restrict__ features,
                                                  const float* __restrict__ W,
                                                  const float* __restrict__ bias,
                                                  const int* __restrict__ knn_idx,
                                                  const float* __restrict__ de,
                                                  float* __restrict__ hmax_g,
                                                  float* __restrict__ hmin_g,
                                                  float* __restrict__ gsum,
                                                  float* __restrict__ gsq) {
    __shared__ __align__(16) float sg[16 * G_CH];
    __shared__ float scomb[2 * OUT_CH];

    const int b   = blockIdx.x >> 7;
    const int qg  = blockIdx.x & 127;
    const int tid = threadIdx.x;
    const int d   = tid & 127;
    const int kh  = tid >> 7;

    float w[G_CH];
#pragma unroll
    for (int c = 0; c < G_CH; ++c) w[c] = W[c * OUT_CH + d];
    const float breg = bias[d];

    float ssum = 0.f, ssq = 0.f;
    const float4* sg4 = (const float4*)sg;

    for (int qq = 0; qq < 16; ++qq) {
        const int q = qg * 16 + qq;
        const int base = b * M_PTS + q;
        for (int j = tid; j < 16 * G_CH; j += 256) {
            int k = j / G_CH;
            int c = j - k * G_CH;
            int nb = knn_idx[base * K_NN + k];
            float v;
            if (c < 4) v = events[((size_t)(b * N_PTS + nb)) * 4 + c] - de[(size_t)base * 4 + c];
            else       v = features[((size_t)(b * N_PTS + nb)) * IN_CH + (c - 4)];
            sg[j] = v;
        }
        __syncthreads();

        float hmax = -1e30f, hmin = 1e30f;
#pragma unroll
        for (int k2 = 0; k2 < 8; ++k2) {
            const int k = kh * 8 + k2;
            float acc = breg;
#pragma unroll
            for (int c4 = 0; c4 < 17; ++c4) {
                float4 g = sg4[k * 17 + c4];
                acc = fmaf(g.x, w[4 * c4 + 0], acc);
                acc = fmaf(g.y, w[4 * c4 + 1], acc);
                acc = fmaf(g.z, w[4 * c4 + 2], acc);
                acc = fmaf(g.w, w[4 * c4 + 3], acc);
            }
            hmax = fmaxf(hmax, acc);
            hmin = fminf(hmin, acc);
            ssum += acc;
            ssq = fmaf(acc, acc, ssq);
        }
        if (kh == 1) { scomb[d] = hmax; scomb[OUT_CH + d] = hmin; }
        __syncthreads();
        if (kh == 0) {
            hmax = fmaxf(hmax, scomb[d]);
            hmin = fminf(hmin, scomb[OUT_CH + d]);
            hmax_g[(size_t)base * OUT_CH + d] = hmax;
            hmin_g[(size_t)base * OUT_CH + d] = hmin;
        }
        __syncthreads();
    }
    if (kh == 1) { scomb[d] = ssum; scomb[OUT_CH + d] = ssq; }
    __syncthreads();
    if (kh == 0) {
        atomicAdd(&gsum[d], ssum + scomb[d]);
        atomicAdd(&gsq[d],  ssq  + scomb[OUT_CH + d]);
    }
}

// ---------------------------------------------------------------------------
// Kernel 4: BN affine + relu + max-over-k via hmax/hmin (unchanged).
// ---------------------------------------------------------------------------
__global__ __launch_bounds__(256) void fin_kernel(const float* __restrict__ hmax_g,
                                                  const float* __restrict__ hmin_g,
                                                  const float* __restrict__ gsum,
                                                  const float* __restrict__ gsq,
                                                  const float* __restrict__ gamma,
                                                  const float* __restrict__ beta,
                                                  float* __restrict__ out) {
    const size_t e = (size_t)blockIdx.x * 256 + threadIdx.x;
    const int d = (int)(e & 127);
    const float inv_cnt = 1.0f / 131072.0f;
    float mu  = gsum[d] * inv_cnt;
    float var = gsq[d] * inv_cnt - mu * mu;
    float a   = gamma[d] * rsqrtf(var + 1e-5f);
    float sh  = fmaf(-mu, a, beta[d]);
    float hv  = (a >= 0.f) ? hmax_g[e] : hmin_g[e];
    float r   = fmaf(a, hv, sh);
    out[32768 + e] = r > 0.f ? r : 0.f;
}

// ---------------------------------------------------------------------------
extern "C" void kernel_launch(void* const* d_in, const int* in_sizes, int n_in,
                              void* d_out, int out_size, void* d_ws, size_t ws_size,
                              hipStream_t stream) {
    const float* events   = (const float*)d_in[0];
    const float* features = (const float*)d_in[1];
    const float* W        = (const float*)d_in[2];
    const float* bias     = (const float*)d_in[3];
    const float* gamma    = (const float*)d_in[4];
    const float* beta     = (const float*)d_in[5];
    float* out = (float*)d_out;
    char* ws = (char*)d_ws;

    int*   down_idx = (int*)ws;                          // 32768 B
    int*   knn_idx  = (int*)(ws + 32768);                // 524288 B
    float* gsum     = (float*)(ws + 32768 + 524288);     // 512 B
    float* gsq      = gsum + OUT_CH;                     // 512 B
    float* hmaxg    = (float*)(ws + 558080);             // 4 MB
    float* hming    = hmaxg + (size_t)4 * M_PTS * OUT_CH;// 4 MB

    (void)hipMemsetAsync(gsum, 0, 2 * OUT_CH * sizeof(float), stream);

    const size_t fps_lds = 32 + 4 * M_PTS + (size_t)N_PTS * sizeof(float4); // 139296
    fps_kernel<<<4, 256, fps_lds, stream>>>((const float4*)events, down_idx, (float4*)out);

    const size_t knn_lds = (size_t)3 * N_PTS * sizeof(float)
                         + (size_t)32 * KCAP * 8 + 128;                      // 131200
    knn_kernel<<<256, 256, knn_lds, stream>>>((const float4*)events, down_idx, knn_idx);

    gmm_kernel<<<512, 256, 0, stream>>>(events, features, W, bias, knn_idx, out,
                                        hmaxg, hming, gsum, gsq);

    fin_kernel<<<4096, 256, 0, stream>>>(hmaxg, hming, gsum, gsq, gamma, beta, out);
}

// Round 10
// 2594.342 us; speedup vs baseline: 1.0781x; 1.0781x over previous
//
#include <hip/hip_runtime.h>

#define N_PTS 8192
#define M_PTS 2048
#define K_NN 16
#define IN_CH 64
#define G_CH 68
#define OUT_CH 128
#define KCAP 128

// Unfusable fp32 ops: inline asm cannot be FMA-contracted by the compiler.
__device__ __forceinline__ float subrn(float a, float b) {
    float r; asm("v_sub_f32 %0, %1, %2" : "=v"(r) : "v"(a), "v"(b)); return r;
}
__device__ __forceinline__ float mulrn(float a, float b) {
    float r; asm("v_mul_f32 %0, %1, %2" : "=v"(r) : "v"(a), "v"(b)); return r;
}
__device__ __forceinline__ float addrn(float a, float b) {
    float r; asm("v_add_f32 %0, %1, %2" : "=v"(r) : "v"(a), "v"(b)); return r;
}
// numpy-exact fp32 squared distance: ((dx*dx + dy*dy) + dz*dz), per-op rounding.
__device__ __forceinline__ float sqdist_rn(float ax, float ay, float az,
                                           float bx, float by, float bz) {
    float dx = subrn(ax, bx);
    float dy = subrn(ay, by);
    float dz = subrn(az, bz);
    return addrn(addrn(mulrn(dx, dx), mulrn(dy, dy)), mulrn(dz, dz));
}

// Packed 2xfp32 ops (VOP3P). Each half is a plain IEEE fp32 op -> numerics
// bit-identical to scalar. Subtraction as a + (-b) (exact sign flip).
typedef float v2f __attribute__((ext_vector_type(2)));
__device__ __forceinline__ v2f pk_add(v2f a, v2f b) {
    v2f r; asm("v_pk_add_f32 %0, %1, %2" : "=v"(r) : "v"(a), "v"(b)); return r;
}
__device__ __forceinline__ v2f pk_mul(v2f a, v2f b) {
    v2f r; asm("v_pk_mul_f32 %0, %1, %2" : "=v"(r) : "v"(a), "v"(b)); return r;
}

// ---- DPP helpers ----------------------------------------------------------
template <int CTRL>
__device__ __forceinline__ float movdpp_f(float x) {
    int r = __builtin_amdgcn_mov_dpp(__float_as_int(x), CTRL, 0xf, 0xf, true);
    return __int_as_float(r);
}
template <int CTRL>
__device__ __forceinline__ int movdpp_i(int x) {
    return __builtin_amdgcn_mov_dpp(x, CTRL, 0xf, 0xf, true);
}
// masked bcast stages: update_dpp with identity old
template <int CTRL, int RM>
__device__ __forceinline__ float dppmaxf_m(float x) {
    int r = __builtin_amdgcn_update_dpp(0, __float_as_int(x), CTRL, RM, 0xf, false);
    return fmaxf(x, __int_as_float(r));   // old=0 safe: dists >= 0
}
template <int CTRL, int RM>
__device__ __forceinline__ int dppmini_m(int x) {
    int r = __builtin_amdgcn_update_dpp(0x7fffffff, x, CTRL, RM, 0xf, false);
    return min(x, r);
}
// full 64-lane max -> valid in lane 63
__device__ __forceinline__ float wave_max64(float x) {
    x = fmaxf(x, movdpp_f<0xB1>(x));   // quad_perm xor1
    x = fmaxf(x, movdpp_f<0x4E>(x));   // quad_perm xor2
    x = fmaxf(x, movdpp_f<0x141>(x));  // row_half_mirror
    x = fmaxf(x, movdpp_f<0x140>(x));  // row_mirror
    x = dppmaxf_m<0x142, 0xa>(x);      // row_bcast15 -> rows 1,3
    x = dppmaxf_m<0x143, 0xc>(x);      // row_bcast31 -> lane63 full
    return x;
}
// full 64-lane min (int) -> valid in lane 63
__device__ __forceinline__ int wave_min64_i(int x) {
    x = min(x, movdpp_i<0xB1>(x));
    x = min(x, movdpp_i<0x4E>(x));
    x = min(x, movdpp_i<0x141>(x));
    x = min(x, movdpp_i<0x140>(x));
    x = dppmini_m<0x142, 0xa>(x);
    x = dppmini_m<0x143, 0xc>(x);
    return x;
}
// 8-lane-group max (lane%8-aligned) -- used by knn
__device__ __forceinline__ float group8_max(float x) {
    x = fmaxf(x, movdpp_f<0xB1>(x));
    x = fmaxf(x, movdpp_f<0x4E>(x));
    x = fmaxf(x, movdpp_f<0x141>(x));
    return x;
}

// ---------------------------------------------------------------------------
// Kernel 1: FPS, one block (512 thr, 8 waves) per batch. Bit-exact fp32
// (no FMA) distance chain; interleaved ownership (pt = j*512 + tid).
// ONE barrier per iteration: each wave computes (wave_max, tie-min global
// idx) fully in-wave (DPP + readlane bcast), publishes an int2 pair to a
// parity-double-buffered LDS slot; after the single barrier all lanes do a
// 3-stage lexicographic DPP group-8 reduce over the 8 pairs (int compare
// valid: dists >= 0 so float bits order as ints). Winner = max dist, tie ->
// min index == np argmax first-occurrence, exact.
// ---------------------------------------------------------------------------
__global__ __launch_bounds__(512) void fps_kernel(const float4* __restrict__ events4,
                                                  int* __restrict__ down_idx,
                                                  float4* __restrict__ out_de) {
    extern __shared__ char smem[];
    int2*   rp   = (int2*)smem;                    // 2 x 8 pairs (parity dbuf)
    int*    ssel = (int*)(smem + 128);             // 2048 ints
    float4* spt  = (float4*)(smem + 128 + 4 * M_PTS);

    const int b = blockIdx.x;
    const int tid = threadIdx.x;
    const int wave = tid >> 6;
    const int lane = tid & 63;
    const float4* ev = events4 + (size_t)b * N_PTS;

    for (int i = tid; i < N_PTS; i += 512) spt[i] = ev[i];
    if (tid == 0) ssel[0] = 0;
    __syncthreads();

    // 16 pts/thread, interleaved: pair pp -> pts (2pp)*512+tid, (2pp+1)*512+tid
    v2f px[8], py[8], pz[8];
    float dist[16];
#pragma unroll
    for (int pp = 0; pp < 8; ++pp) {
        float4 f0 = spt[(2 * pp) * 512 + tid];
        float4 f1 = spt[(2 * pp + 1) * 512 + tid];
        px[pp] = (v2f){f0.x, f1.x};
        py[pp] = (v2f){f0.y, f1.y};
        pz[pp] = (v2f){f0.z, f1.z};
        dist[2 * pp] = 1e10f; dist[2 * pp + 1] = 1e10f;   // reference init
    }

    int last = 0;
    for (int i = 1; i < M_PTS; ++i) {
        float4 L = spt[last];                     // uniform ds_read_b128
        const float nlx = -L.x, nly = -L.y, nlz = -L.z;   // exact sign flips
        const v2f nx2 = (v2f){nlx, nlx};
        const v2f ny2 = (v2f){nly, nly};
        const v2f nz2 = (v2f){nlz, nlz};
#pragma unroll
        for (int pp = 0; pp < 8; ++pp) {
            v2f dx = pk_add(px[pp], nx2);         // == px - lx, exact
            v2f dy = pk_add(py[pp], ny2);
            v2f dz = pk_add(pz[pp], nz2);
            v2f s  = pk_add(pk_add(pk_mul(dx, dx), pk_mul(dy, dy)), pk_mul(dz, dz));
            dist[2 * pp]     = fminf(dist[2 * pp],     s.x);
            dist[2 * pp + 1] = fminf(dist[2 * pp + 1], s.y);
        }
        // per-thread max (tree)
        float t0[8];
#pragma unroll
        for (int j = 0; j < 8; ++j) t0[j] = fmaxf(dist[2 * j], dist[2 * j + 1]);
#pragma unroll
        for (int j = 0; j < 4; ++j) t0[j] = fmaxf(t0[2 * j], t0[2 * j + 1]);
        float bd = fmaxf(fmaxf(t0[0], t0[1]), fmaxf(t0[2], t0[3]));

        // in-wave: wave max -> broadcast via readlane(63)
        float wm = wave_max64(bd);
        float wmb = __int_as_float(__builtin_amdgcn_readlane(__float_as_int(wm), 63));

        // candidates (bd == wave max) resolve smallest local j -> global idx;
        // wave-min gives this wave's tie-min index (valid in lane 63)
        int myidx = 0x7fffffff;
        if (bd == wmb) {
            int jm = 0;
#pragma unroll
            for (int j = 15; j >= 0; --j) if (dist[j] == bd) jm = j;
            myidx = jm * 512 + tid;
        }
        int wmin = wave_min64_i(myidx);

        // lane 63 publishes (dist_bits, idx); parity double-buffer
        if (lane == 63) rp[(i & 1) * 8 + wave] = make_int2(__float_as_int(wmb), wmin);
        __syncthreads();                          // the ONLY barrier

        // block reduce: each lane reads pair (lane&7), 3-stage lexicographic
        int2 pr = rp[(i & 1) * 8 + (lane & 7)];
        int db = pr.x, ib = pr.y;
        {
            int od = movdpp_i<0xB1>(db), oi = movdpp_i<0xB1>(ib);
            bool t = (od > db) || (od == db && oi < ib);
            db = t ? od : db; ib = t ? oi : ib;
            od = movdpp_i<0x4E>(db); oi = movdpp_i<0x4E>(ib);
            t = (od > db) || (od == db && oi < ib);
            db = t ? od : db; ib = t ? oi : ib;
            od = movdpp_i<0x141>(db); oi = movdpp_i<0x141>(ib);
            t = (od > db) || (od == db && oi < ib);
            db = t ? od : db; ib = t ? oi : ib;
        }
        last = ib;                                // uniform winner
        if (tid == 0) ssel[i] = last;
    }
    __syncthreads();

    for (int i = tid; i < M_PTS; i += 512) {
        int s = ssel[i];
        down_idx[b * M_PTS + i] = s;
        out_de[(size_t)b * M_PTS + i] = spt[s];
    }
}

// ---------------------------------------------------------------------------
// Kernel 2: 16-NN, divergence-free threshold algorithm (unchanged from R8).
// ---------------------------------------------------------------------------
__global__ __launch_bounds__(256) void knn_kernel(const float4* __restrict__ events4,
                                                  const int* __restrict__ down_idx,
                                                  int* __restrict__ knn_idx) {
    extern __shared__ char smem[];
    float* sx   = (float*)smem;
    float* sy   = sx + N_PTS;
    float* sz   = sy + N_PTS;
    float* cd   = sz + N_PTS;
    int*   ci   = (int*)(cd + 32 * KCAP);
    int*   scnt = (int*)(ci + 32 * KCAP);

    const int b    = blockIdx.x >> 6;
    const int qg   = blockIdx.x & 63;
    const int tid  = threadIdx.x;
    const int ql   = tid >> 3;
    const int part = tid & 7;

    const float4* ev = events4 + (size_t)b * N_PTS;
    for (int i = tid; i < N_PTS; i += 256) {
        float4 e = ev[i];
        sx[i] = e.x; sy[i] = e.y; sz[i] = e.z;
    }
    if (tid < 32) scnt[tid] = 0;
    __syncthreads();

    const int q  = qg * 32 + ql;
    const int qi = down_idx[b * M_PTS + q];
    const float qx = sx[qi], qy = sy[qi], qz = sz[qi];

    float m1 = 1e30f, m2 = 1e30f;
    for (int i = 0; i < N_PTS / 8; ++i) {
        const int p = i * 8 + part;
        float d = sqdist_rn(sx[p], sy[p], sz[p], qx, qy, qz);
        float lo = fminf(m1, d);
        m2 = fminf(m2, fmaxf(m1, d));
        m1 = lo;
    }
    const float T = group8_max(m2);

    for (int i = 0; i < N_PTS / 8; ++i) {
        const int p = i * 8 + part;
        float d = sqdist_rn(sx[p], sy[p], sz[p], qx, qy, qz);
        if (d <= T) {
            int pos = atomicAdd(&scnt[ql], 1);
            if (pos < KCAP) { cd[ql * KCAP + pos] = d; ci[ql * KCAP + pos] = p; }
        }
    }
    __syncthreads();

    if (part == 0) {
        float nd[16]; int ni[16];
#pragma unroll
        for (int j = 0; j < 16; ++j) { nd[j] = 1e30f; ni[j] = 0x7fffffff; }
        float wmax = 1e30f; int widx = 0x7fffffff; int wslot = 0;
        const int n = scnt[ql];
        const int lim = (n <= KCAP) ? n : 0;
        for (int t = 0; t < lim; ++t) {
            float d = cd[ql * KCAP + t];
            int   p = ci[ql * KCAP + t];
            if (d < wmax || (d == wmax && p < widx)) {
#pragma unroll
                for (int j = 0; j < 16; ++j) if (j == wslot) { nd[j] = d; ni[j] = p; }
                float m_ = -1.0f; int mix_ = -1; int ms_ = 0;
#pragma unroll
                for (int j = 0; j < 16; ++j)
                    if (nd[j] > m_ || (nd[j] == m_ && ni[j] > mix_)) { m_ = nd[j]; mix_ = ni[j]; ms_ = j; }
                wmax = m_; widx = mix_; wslot = ms_;
            }
        }
        if (n > KCAP) {
            for (int p = 0; p < N_PTS; ++p) {
                float d = sqdist_rn(sx[p], sy[p], sz[p], qx, qy, qz);
                if (d < wmax || (d == wmax && p < widx)) {
#pragma unroll
                    for (int j = 0; j < 16; ++j) if (j == wslot) { nd[j] = d; ni[j] = p; }
                    float m_ = -1.0f; int mix_ = -1; int ms_ = 0;
#pragma unroll
                    for (int j = 0; j < 16; ++j)
                        if (nd[j] > m_ || (nd[j] == m_ && ni[j] > mix_)) { m_ = nd[j]; mix_ = ni[j]; ms_ = j; }
                    wmax = m_; widx = mix_; wslot = ms_;
                }
            }
        }
        int* out = knn_idx + ((size_t)(b * M_PTS + q)) * K_NN;
#pragma unroll
        for (int j = 0; j < 16; ++j) out[j] = ni[j];
    }
}

// ---------------------------------------------------------------------------
// Kernel 3: gather + per-query (16x68)@(68x128) matmul + bias (unchanged).
// ---------------------------------------------------------------------------
__global__ __launch_bounds__(256) void gmm_kernel(const float* __restrict__ events,
                                                  const float* __restrict__ features,
                                                  const float* __restrict__ W,
                                                  const float* __restrict__ bias,
                                                  const int* __restrict__ knn_idx,
                                                  const float* __restrict__ de,
                                                  float* __restrict__ hmax_g,
                                                  float* __restrict__ hmin_g,
                                                  float* __restrict__ gsum,
                                                  float* __restrict__ gsq) {
    __shared__ __align__(16) float sg[16 * G_CH];
    __shared__ float scomb[2 * OUT_CH];

    const int b   = blockIdx.x >> 7;
    const int qg  = blockIdx.x & 127;
    const int tid = threadIdx.x;
    const int d   = tid & 127;
    const int kh  = tid >> 7;

    float w[G_CH];
#pragma unroll
    for (int c = 0; c < G_CH; ++c) w[c] = W[c * OUT_CH + d];
    const float breg = bias[d];

    float ssum = 0.f, ssq = 0.f;
    const float4* sg4 = (const float4*)sg;

    for (int qq = 0; qq < 16; ++qq) {
        const int q = qg * 16 + qq;
        const int base = b * M_PTS + q;
        for (int j = tid; j < 16 * G_CH; j += 256) {
            int k = j / G_CH;
            int c = j - k * G_CH;
            int nb = knn_idx[base * K_NN + k];
            float v;
            if (c < 4) v = events[((size_t)(b * N_PTS + nb)) * 4 + c] - de[(size_t)base * 4 + c];
            else       v = features[((size_t)(b * N_PTS + nb)) * IN_CH + (c - 4)];
            sg[j] = v;
        }
        __syncthreads();

        float hmax = -1e30f, hmin = 1e30f;
#pragma unroll
        for (int k2 = 0; k2 < 8; ++k2) {
            const int k = kh * 8 + k2;
            float acc = breg;
#pragma unroll
            for (int c4 = 0; c4 < 17; ++c4) {
                float4 g = sg4[k * 17 + c4];
                acc = fmaf(g.x, w[4 * c4 + 0], acc);
                acc = fmaf(g.y, w[4 * c4 + 1], acc);
                acc = fmaf(g.z, w[4 * c4 + 2], acc);
                acc = fmaf(g.w, w[4 * c4 + 3], acc);
            }
            hmax = fmaxf(hmax, acc);
            hmin = fminf(hmin, acc);
            ssum += acc;
            ssq = fmaf(acc, acc, ssq);
        }
        if (kh == 1) { scomb[d] = hmax; scomb[OUT_CH + d] = hmin; }
        __syncthreads();
        if (kh == 0) {
            hmax = fmaxf(hmax, scomb[d]);
            hmin = fminf(hmin, scomb[OUT_CH + d]);
            hmax_g[(size_t)base * OUT_CH + d] = hmax;
            hmin_g[(size_t)base * OUT_CH + d] = hmin;
        }
        __syncthreads();
    }
    if (kh == 1) { scomb[d] = ssum; scomb[OUT_CH + d] = ssq; }
    __syncthreads();
    if (kh == 0) {
        atomicAdd(&gsum[d], ssum + scomb[d]);
        atomicAdd(&gsq[d],  ssq  + scomb[OUT_CH + d]);
    }
}

// ---------------------------------------------------------------------------
// Kernel 4: BN affine + relu + max-over-k via hmax/hmin (unchanged).
// ---------------------------------------------------------------------------
__global__ __launch_bounds__(256) void fin_kernel(const float* __restrict__ hmax_g,
                                                  const float* __restrict__ hmin_g,
                                                  const float* __restrict__ gsum,
                                                  const float* __restrict__ gsq,
                                                  const float* __restrict__ gamma,
                                                  const float* __restrict__ beta,
                                                  float* __restrict__ out) {
    const size_t e = (size_t)blockIdx.x * 256 + threadIdx.x;
    const int d = (int)(e & 127);
    const float inv_cnt = 1.0f / 131072.0f;
    float mu  = gsum[d] * inv_cnt;
    float var = gsq[d] * inv_cnt - mu * mu;
    float a   = gamma[d] * rsqrtf(var + 1e-5f);
    float sh  = fmaf(-mu, a, beta[d]);
    float hv  = (a >= 0.f) ? hmax_g[e] : hmin_g[e];
    float r   = fmaf(a, hv, sh);
    out[32768 + e] = r > 0.f ? r : 0.f;
}

// ---------------------------------------------------------------------------
extern "C" void kernel_launch(void* const* d_in, const int* in_sizes, int n_in,
                              void* d_out, int out_size, void* d_ws, size_t ws_size,
                              hipStream_t stream) {
    const float* events   = (const float*)d_in[0];
    const float* features = (const float*)d_in[1];
    const float* W        = (const float*)d_in[2];
    const float* bias     = (const float*)d_in[3];
    const float* gamma    = (const float*)d_in[4];
    const float* beta     = (const float*)d_in[5];
    float* out = (float*)d_out;
    char* ws = (char*)d_ws;

    int*   down_idx = (int*)ws;                          // 32768 B
    int*   knn_idx  = (int*)(ws + 32768);                // 524288 B
    float* gsum     = (float*)(ws + 32768 + 524288);     // 512 B
    float* gsq      = gsum + OUT_CH;                     // 512 B
    float* hmaxg    = (float*)(ws + 558080);             // 4 MB
    float* hming    = hmaxg + (size_t)4 * M_PTS * OUT_CH;// 4 MB

    (void)hipMemsetAsync(gsum, 0, 2 * OUT_CH * sizeof(float), stream);

    const size_t fps_lds = 128 + 4 * M_PTS + (size_t)N_PTS * sizeof(float4); // 139392
    fps_kernel<<<4, 512, fps_lds, stream>>>((const float4*)events, down_idx, (float4*)out);

    const size_t knn_lds = (size_t)3 * N_PTS * sizeof(float)
                         + (size_t)32 * KCAP * 8 + 128;                      // 131200
    knn_kernel<<<256, 256, knn_lds, stream>>>((const float4*)events, down_idx, knn_idx);

    gmm_kernel<<<512, 256, 0, stream>>>(events, features, W, bias, knn_idx, out,
                                        hmaxg, hming, gsum, gsq);

    fin_kernel<<<4096, 256, 0, stream>>>(hmaxg, hming, gsum, gsq, gamma, beta, out);
}

// Round 11
// 2426.642 us; speedup vs baseline: 1.1526x; 1.0691x over previous
//
#include <hip/hip_runtime.h>

#define N_PTS 8192
#define M_PTS 2048
#define K_NN 16
#define IN_CH 64
#define G_CH 68
#define OUT_CH 128
#define KCAP 128

// Unfusable fp32 ops: inline asm cannot be FMA-contracted by the compiler.
__device__ __forceinline__ float subrn(float a, float b) {
    float r; asm("v_sub_f32 %0, %1, %2" : "=v"(r) : "v"(a), "v"(b)); return r;
}
__device__ __forceinline__ float mulrn(float a, float b) {
    float r; asm("v_mul_f32 %0, %1, %2" : "=v"(r) : "v"(a), "v"(b)); return r;
}
__device__ __forceinline__ float addrn(float a, float b) {
    float r; asm("v_add_f32 %0, %1, %2" : "=v"(r) : "v"(a), "v"(b)); return r;
}
// numpy-exact fp32 squared distance: ((dx*dx + dy*dy) + dz*dz), per-op rounding.
__device__ __forceinline__ float sqdist_rn(float ax, float ay, float az,
                                           float bx, float by, float bz) {
    float dx = subrn(ax, bx);
    float dy = subrn(ay, by);
    float dz = subrn(az, bz);
    return addrn(addrn(mulrn(dx, dx), mulrn(dy, dy)), mulrn(dz, dz));
}

// Packed 2xfp32 ops (VOP3P). Each half is a plain IEEE fp32 op -> numerics
// bit-identical to scalar. Subtraction as a + (-b) (exact sign flip).
typedef float v2f __attribute__((ext_vector_type(2)));
__device__ __forceinline__ v2f pk_add(v2f a, v2f b) {
    v2f r; asm("v_pk_add_f32 %0, %1, %2" : "=v"(r) : "v"(a), "v"(b)); return r;
}
__device__ __forceinline__ v2f pk_mul(v2f a, v2f b) {
    v2f r; asm("v_pk_mul_f32 %0, %1, %2" : "=v"(r) : "v"(a), "v"(b)); return r;
}

// ---- DPP helpers ----------------------------------------------------------
template <int CTRL>
__device__ __forceinline__ float movdpp_f(float x) {
    int r = __builtin_amdgcn_mov_dpp(__float_as_int(x), CTRL, 0xf, 0xf, true);
    return __int_as_float(r);
}
// masked bcast stages for wave max: update_dpp old=0 (max with 0 safe, d>=0)
template <int CTRL, int RM>
__device__ __forceinline__ float dppmaxf_m(float x) {
    int r = __builtin_amdgcn_update_dpp(0, __float_as_int(x), CTRL, RM, 0xf, false);
    return fmaxf(x, __int_as_float(r));
}
// full 64-lane max -> valid in lane 63
__device__ __forceinline__ float wave_max64(float x) {
    x = fmaxf(x, movdpp_f<0xB1>(x));   // quad_perm xor1
    x = fmaxf(x, movdpp_f<0x4E>(x));   // quad_perm xor2
    x = fmaxf(x, movdpp_f<0x141>(x));  // row_half_mirror
    x = fmaxf(x, movdpp_f<0x140>(x));  // row_mirror
    x = dppmaxf_m<0x142, 0xa>(x);      // row_bcast15 -> rows 1,3
    x = dppmaxf_m<0x143, 0xc>(x);      // row_bcast31 -> lane63 full
    return x;
}
// 8-lane-group max (lane%8-aligned)
__device__ __forceinline__ float group8_max(float x) {
    x = fmaxf(x, movdpp_f<0xB1>(x));
    x = fmaxf(x, movdpp_f<0x4E>(x));
    x = fmaxf(x, movdpp_f<0x141>(x));
    return x;
}

// ---------------------------------------------------------------------------
// Kernel 1: FPS, one block (512 thr, 8 waves) per batch. Bit-exact fp32
// (no FMA) distance chain; interleaved ownership (pt = j*512 + tid).
// R8 two-barrier structure (best measured) with single-slot LDS atomicMin
// winner publish: candidates (bd == block max) resolve their smallest local
// j and atomicMin the GLOBAL index -> exact np argmax first-occurrence.
// ---------------------------------------------------------------------------
__global__ __launch_bounds__(512) void fps_kernel(const float4* __restrict__ events4,
                                                  int* __restrict__ down_idx,
                                                  float4* __restrict__ out_de) {
    extern __shared__ char smem[];
    float*  rv   = (float*)smem;                   // 8 floats: wave-max partials
    int*    wsl  = (int*)(smem + 32);              // 2 ints: winner slot (parity)
    int*    ssel = (int*)(smem + 64);              // 2048 ints
    float4* spt  = (float4*)(smem + 64 + 4 * M_PTS);

    const int b = blockIdx.x;
    const int tid = threadIdx.x;
    const int wave = tid >> 6;
    const int lane = tid & 63;
    const float4* ev = events4 + (size_t)b * N_PTS;

    for (int i = tid; i < N_PTS; i += 512) spt[i] = ev[i];
    if (tid == 0) { ssel[0] = 0; wsl[0] = 0x7fffffff; wsl[1] = 0x7fffffff; }
    __syncthreads();

    // 16 pts/thread, interleaved: pair pp -> pts (2pp)*512+tid, (2pp+1)*512+tid
    v2f px[8], py[8], pz[8];
    float dist[16];
#pragma unroll
    for (int pp = 0; pp < 8; ++pp) {
        float4 f0 = spt[(2 * pp) * 512 + tid];
        float4 f1 = spt[(2 * pp + 1) * 512 + tid];
        px[pp] = (v2f){f0.x, f1.x};
        py[pp] = (v2f){f0.y, f1.y};
        pz[pp] = (v2f){f0.z, f1.z};
        dist[2 * pp] = 1e10f; dist[2 * pp + 1] = 1e10f;   // reference init
    }

    int last = 0;
    for (int i = 1; i < M_PTS; ++i) {
        float4 L = spt[last];                     // uniform ds_read_b128
        const float nlx = -L.x, nly = -L.y, nlz = -L.z;   // exact sign flips
        const v2f nx2 = (v2f){nlx, nlx};
        const v2f ny2 = (v2f){nly, nly};
        const v2f nz2 = (v2f){nlz, nlz};
#pragma unroll
        for (int pp = 0; pp < 8; ++pp) {
            v2f dx = pk_add(px[pp], nx2);         // == px - lx, exact
            v2f dy = pk_add(py[pp], ny2);
            v2f dz = pk_add(pz[pp], nz2);
            v2f s  = pk_add(pk_add(pk_mul(dx, dx), pk_mul(dy, dy)), pk_mul(dz, dz));
            dist[2 * pp]     = fminf(dist[2 * pp],     s.x);
            dist[2 * pp + 1] = fminf(dist[2 * pp + 1], s.y);
        }
        // per-thread max (tree)
        float t0[8];
#pragma unroll
        for (int j = 0; j < 8; ++j) t0[j] = fmaxf(dist[2 * j], dist[2 * j + 1]);
#pragma unroll
        for (int j = 0; j < 4; ++j) t0[j] = fmaxf(t0[2 * j], t0[2 * j + 1]);
        float bd = fmaxf(fmaxf(t0[0], t0[1]), fmaxf(t0[2], t0[3]));

        // phase A: block max of bd
        float wm = wave_max64(bd);
        if (lane == 63) rv[wave] = wm;
        __syncthreads();                          // B1
        float bm = group8_max(rv[lane & 7]);      // uniform block max

        // phase B: candidates resolve smallest local j, atomicMin global idx
        if (bd == bm) {
            int jm = 0;
#pragma unroll
            for (int j = 15; j >= 0; --j) if (dist[j] == bd) jm = j;
            atomicMin(&wsl[i & 1], jm * 512 + tid);
        }
        __syncthreads();                          // B2
        last = wsl[i & 1];
        if (tid == 0) { ssel[i] = last; wsl[(i + 1) & 1] = 0x7fffffff; }
    }
    __syncthreads();

    for (int i = tid; i < M_PTS; i += 512) {
        int s = ssel[i];
        down_idx[b * M_PTS + i] = s;
        out_de[(size_t)b * M_PTS + i] = spt[s];
    }
}

// ---------------------------------------------------------------------------
// Kernel 2: 16-NN, divergence-free threshold algorithm. LDS coords packed
// as float2(x,y) + z: 2 LDS reads/point instead of 3 on both scan passes.
// ---------------------------------------------------------------------------
__global__ __launch_bounds__(256) void knn_kernel(const float4* __restrict__ events4,
                                                  const int* __restrict__ down_idx,
                                                  int* __restrict__ knn_idx) {
    extern __shared__ char smem[];
    float2* sxy  = (float2*)smem;                    // 8192 float2 (64 KB)
    float*  sz   = (float*)(smem + N_PTS * 8);       // 8192 floats (32 KB)
    float*  cd   = sz + N_PTS;                       // 32*KCAP floats
    int*    ci   = (int*)(cd + 32 * KCAP);           // 32*KCAP ints
    int*    scnt = (int*)(ci + 32 * KCAP);           // 32 ints

    const int b    = blockIdx.x >> 6;
    const int qg   = blockIdx.x & 63;
    const int tid  = threadIdx.x;
    const int ql   = tid >> 3;
    const int part = tid & 7;

    const float4* ev = events4 + (size_t)b * N_PTS;
    for (int i = tid; i < N_PTS; i += 256) {
        float4 e = ev[i];
        sxy[i] = (float2){e.x, e.y}; sz[i] = e.z;
    }
    if (tid < 32) scnt[tid] = 0;
    __syncthreads();

    const int q  = qg * 32 + ql;
    const int qi = down_idx[b * M_PTS + q];
    const float2 qxy = sxy[qi];
    const float qx = qxy.x, qy = qxy.y, qz = sz[qi];

    float m1 = 1e30f, m2 = 1e30f;
    for (int i = 0; i < N_PTS / 8; ++i) {
        const int p = i * 8 + part;
        float2 pxy = sxy[p];
        float d = sqdist_rn(pxy.x, pxy.y, sz[p], qx, qy, qz);
        float lo = fminf(m1, d);
        m2 = fminf(m2, fmaxf(m1, d));
        m1 = lo;
    }
    const float T = group8_max(m2);

    for (int i = 0; i < N_PTS / 8; ++i) {
        const int p = i * 8 + part;
        float2 pxy = sxy[p];
        float d = sqdist_rn(pxy.x, pxy.y, sz[p], qx, qy, qz);
        if (d <= T) {
            int pos = atomicAdd(&scnt[ql], 1);
            if (pos < KCAP) { cd[ql * KCAP + pos] = d; ci[ql * KCAP + pos] = p; }
        }
    }
    __syncthreads();

    if (part == 0) {
        float nd[16]; int ni[16];
#pragma unroll
        for (int j = 0; j < 16; ++j) { nd[j] = 1e30f; ni[j] = 0x7fffffff; }
        float wmax = 1e30f; int widx = 0x7fffffff; int wslot = 0;
        const int n = scnt[ql];
        const int lim = (n <= KCAP) ? n : 0;
        for (int t = 0; t < lim; ++t) {
            float d = cd[ql * KCAP + t];
            int   p = ci[ql * KCAP + t];
            if (d < wmax || (d == wmax && p < widx)) {
#pragma unroll
                for (int j = 0; j < 16; ++j) if (j == wslot) { nd[j] = d; ni[j] = p; }
                float m_ = -1.0f; int mix_ = -1; int ms_ = 0;
#pragma unroll
                for (int j = 0; j < 16; ++j)
                    if (nd[j] > m_ || (nd[j] == m_ && ni[j] > mix_)) { m_ = nd[j]; mix_ = ni[j]; ms_ = j; }
                wmax = m_; widx = mix_; wslot = ms_;
            }
        }
        if (n > KCAP) {   // exact serial fallback (never expected)
            for (int p = 0; p < N_PTS; ++p) {
                float2 pxy = sxy[p];
                float d = sqdist_rn(pxy.x, pxy.y, sz[p], qx, qy, qz);
                if (d < wmax || (d == wmax && p < widx)) {
#pragma unroll
                    for (int j = 0; j < 16; ++j) if (j == wslot) { nd[j] = d; ni[j] = p; }
                    float m_ = -1.0f; int mix_ = -1; int ms_ = 0;
#pragma unroll
                    for (int j = 0; j < 16; ++j)
                        if (nd[j] > m_ || (nd[j] == m_ && ni[j] > mix_)) { m_ = nd[j]; mix_ = ni[j]; ms_ = j; }
                    wmax = m_; widx = mix_; wslot = ms_;
                }
            }
        }
        int* out = knn_idx + ((size_t)(b * M_PTS + q)) * K_NN;
#pragma unroll
        for (int j = 0; j < 16; ++j) out[j] = ni[j];
    }
}

// ---------------------------------------------------------------------------
// Kernel 3: gather + per-query (16x68)@(68x128) matmul + bias. Staging is
// now float4 (events row, de row, feature rows all 16B-aligned at 4-float
// offsets): 4x fewer global loads + ds_write_b128.
// ---------------------------------------------------------------------------
__global__ __launch_bounds__(256) void gmm_kernel(const float4* __restrict__ events4,
                                                  const float4* __restrict__ feat4,
                                                  const float* __restrict__ W,
                                                  const float* __restrict__ bias,
                                                  const int* __restrict__ knn_idx,
                                                  const float4* __restrict__ de4,
                                                  float* __restrict__ hmax_g,
                                                  float* __restrict__ hmin_g,
                                                  float* __restrict__ gsum,
                                                  float* __restrict__ gsq) {
    __shared__ __align__(16) float sg[16 * G_CH];
    __shared__ float scomb[2 * OUT_CH];

    const int b   = blockIdx.x >> 7;
    const int qg  = blockIdx.x & 127;
    const int tid = threadIdx.x;
    const int d   = tid & 127;
    const int kh  = tid >> 7;

    float w[G_CH];
#pragma unroll
    for (int c = 0; c < G_CH; ++c) w[c] = W[c * OUT_CH + d];
    const float breg = bias[d];

    float ssum = 0.f, ssq = 0.f;
    const float4* sg4r = (const float4*)sg;
    float4* sg4w = (float4*)sg;

    for (int qq = 0; qq < 16; ++qq) {
        const int q = qg * 16 + qq;
        const int base = b * M_PTS + q;
        // float4 staging: j4 indexes 16 k-rows x 17 float4-chunks
        for (int j4 = tid; j4 < 16 * 17; j4 += 256) {
            int k = j4 / 17;
            int c4 = j4 - k * 17;
            int nb = knn_idx[base * K_NN + k];
            float4 v;
            if (c4 == 0) {
                float4 e = events4[(size_t)b * N_PTS + nb];
                float4 d0 = de4[base];
                v = (float4){e.x - d0.x, e.y - d0.y, e.z - d0.z, e.w - d0.w};
            } else {
                v = feat4[((size_t)(b * N_PTS + nb)) * 16 + (c4 - 1)];
            }
            sg4w[j4] = v;
        }
        __syncthreads();

        float hmax = -1e30f, hmin = 1e30f;
#pragma unroll
        for (int k2 = 0; k2 < 8; ++k2) {
            const int k = kh * 8 + k2;
            float acc = breg;
#pragma unroll
            for (int c4 = 0; c4 < 17; ++c4) {
                float4 g = sg4r[k * 17 + c4];
                acc = fmaf(g.x, w[4 * c4 + 0], acc);
                acc = fmaf(g.y, w[4 * c4 + 1], acc);
                acc = fmaf(g.z, w[4 * c4 + 2], acc);
                acc = fmaf(g.w, w[4 * c4 + 3], acc);
            }
            hmax = fmaxf(hmax, acc);
            hmin = fminf(hmin, acc);
            ssum += acc;
            ssq = fmaf(acc, acc, ssq);
        }
        if (kh == 1) { scomb[d] = hmax; scomb[OUT_CH + d] = hmin; }
        __syncthreads();
        if (kh == 0) {
            hmax = fmaxf(hmax, scomb[d]);
            hmin = fminf(hmin, scomb[OUT_CH + d]);
            hmax_g[(size_t)base * OUT_CH + d] = hmax;
            hmin_g[(size_t)base * OUT_CH + d] = hmin;
        }
        __syncthreads();
    }
    if (kh == 1) { scomb[d] = ssum; scomb[OUT_CH + d] = ssq; }
    __syncthreads();
    if (kh == 0) {
        atomicAdd(&gsum[d], ssum + scomb[d]);
        atomicAdd(&gsq[d],  ssq  + scomb[OUT_CH + d]);
    }
}

// ---------------------------------------------------------------------------
// Kernel 4: BN affine + relu + max-over-k via hmax/hmin (affine monotone).
// ---------------------------------------------------------------------------
__global__ __launch_bounds__(256) void fin_kernel(const float* __restrict__ hmax_g,
                                                  const float* __restrict__ hmin_g,
                                                  const float* __restrict__ gsum,
                                                  const float* __restrict__ gsq,
                                                  const float* __restrict__ gamma,
                                                  const float* __restrict__ beta,
                                                  float* __restrict__ out) {
    const size_t e = (size_t)blockIdx.x * 256 + threadIdx.x;
    const int d = (int)(e & 127);
    const float inv_cnt = 1.0f / 131072.0f;
    float mu  = gsum[d] * inv_cnt;
    float var = gsq[d] * inv_cnt - mu * mu;
    float a   = gamma[d] * rsqrtf(var + 1e-5f);
    float sh  = fmaf(-mu, a, beta[d]);
    float hv  = (a >= 0.f) ? hmax_g[e] : hmin_g[e];
    float r   = fmaf(a, hv, sh);
    out[32768 + e] = r > 0.f ? r : 0.f;
}

// ---------------------------------------------------------------------------
extern "C" void kernel_launch(void* const* d_in, const int* in_sizes, int n_in,
                              void* d_out, int out_size, void* d_ws, size_t ws_size,
                              hipStream_t stream) {
    const float* events   = (const float*)d_in[0];
    const float* features = (const float*)d_in[1];
    const float* W        = (const float*)d_in[2];
    const float* bias     = (const float*)d_in[3];
    const float* gamma    = (const float*)d_in[4];
    const float* beta     = (const float*)d_in[5];
    float* out = (float*)d_out;
    char* ws = (char*)d_ws;

    int*   down_idx = (int*)ws;                          // 32768 B
    int*   knn_idx  = (int*)(ws + 32768);                // 524288 B
    float* gsum     = (float*)(ws + 32768 + 524288);     // 512 B
    float* gsq      = gsum + OUT_CH;                     // 512 B
    float* hmaxg    = (float*)(ws + 558080);             // 4 MB
    float* hming    = hmaxg + (size_t)4 * M_PTS * OUT_CH;// 4 MB

    (void)hipMemsetAsync(gsum, 0, 2 * OUT_CH * sizeof(float), stream);

    const size_t fps_lds = 64 + 4 * M_PTS + (size_t)N_PTS * sizeof(float4); // 139328
    fps_kernel<<<4, 512, fps_lds, stream>>>((const float4*)events, down_idx, (float4*)out);

    const size_t knn_lds = (size_t)N_PTS * 8 + (size_t)N_PTS * 4
                         + (size_t)32 * KCAP * 8 + 128;                      // 131200
    knn_kernel<<<256, 256, knn_lds, stream>>>((const float4*)events, down_idx, knn_idx);

    gmm_kernel<<<512, 256, 0, stream>>>((const float4*)events, (const float4*)features,
                                        W, bias, knn_idx, (const float4*)out,
                                        hmaxg, hming, gsum, gsq);

    fin_kernel<<<4096, 256, 0, stream>>>(hmaxg, hming, gsum, gsq, gamma, beta, out);
}

// Round 12
// 2415.594 us; speedup vs baseline: 1.1579x; 1.0046x over previous
//
#include <hip/hip_runtime.h>

#define N_PTS 8192
#define M_PTS 2048
#define K_NN 16
#define IN_CH 64
#define G_CH 68
#define OUT_CH 128
#define KCAP 128

// Unfusable fp32 ops: inline asm cannot be FMA-contracted by the compiler.
__device__ __forceinline__ float subrn(float a, float b) {
    float r; asm("v_sub_f32 %0, %1, %2" : "=v"(r) : "v"(a), "v"(b)); return r;
}
__device__ __forceinline__ float mulrn(float a, float b) {
    float r; asm("v_mul_f32 %0, %1, %2" : "=v"(r) : "v"(a), "v"(b)); return r;
}
__device__ __forceinline__ float addrn(float a, float b) {
    float r; asm("v_add_f32 %0, %1, %2" : "=v"(r) : "v"(a), "v"(b)); return r;
}
// numpy-exact fp32 squared distance: ((dx*dx + dy*dy) + dz*dz), per-op rounding.
__device__ __forceinline__ float sqdist_rn(float ax, float ay, float az,
                                           float bx, float by, float bz) {
    float dx = subrn(ax, bx);
    float dy = subrn(ay, by);
    float dz = subrn(az, bz);
    return addrn(addrn(mulrn(dx, dx), mulrn(dy, dy)), mulrn(dz, dz));
}

// Packed 2xfp32 ops (VOP3P). Each half is a plain IEEE fp32 op -> numerics
// bit-identical to scalar. Subtraction as a + (-b) (exact sign flip).
typedef float v2f __attribute__((ext_vector_type(2)));
__device__ __forceinline__ v2f pk_add(v2f a, v2f b) {
    v2f r; asm("v_pk_add_f32 %0, %1, %2" : "=v"(r) : "v"(a), "v"(b)); return r;
}
__device__ __forceinline__ v2f pk_mul(v2f a, v2f b) {
    v2f r; asm("v_pk_mul_f32 %0, %1, %2" : "=v"(r) : "v"(a), "v"(b)); return r;
}

// ---- DPP helpers ----------------------------------------------------------
template <int CTRL>
__device__ __forceinline__ float movdpp_f(float x) {
    int r = __builtin_amdgcn_mov_dpp(__float_as_int(x), CTRL, 0xf, 0xf, true);
    return __int_as_float(r);
}
// masked bcast stages for wave max: update_dpp old=0 (max with 0 safe, d>=0)
template <int CTRL, int RM>
__device__ __forceinline__ float dppmaxf_m(float x) {
    int r = __builtin_amdgcn_update_dpp(0, __float_as_int(x), CTRL, RM, 0xf, false);
    return fmaxf(x, __int_as_float(r));
}
// full 64-lane max -> valid in lane 63
__device__ __forceinline__ float wave_max64(float x) {
    x = fmaxf(x, movdpp_f<0xB1>(x));   // quad_perm xor1
    x = fmaxf(x, movdpp_f<0x4E>(x));   // quad_perm xor2
    x = fmaxf(x, movdpp_f<0x141>(x));  // row_half_mirror
    x = fmaxf(x, movdpp_f<0x140>(x));  // row_mirror
    x = dppmaxf_m<0x142, 0xa>(x);      // row_bcast15 -> rows 1,3
    x = dppmaxf_m<0x143, 0xc>(x);      // row_bcast31 -> lane63 full
    return x;
}
// 8-lane-group max (lane%8-aligned)
__device__ __forceinline__ float group8_max(float x) {
    x = fmaxf(x, movdpp_f<0xB1>(x));
    x = fmaxf(x, movdpp_f<0x4E>(x));
    x = fmaxf(x, movdpp_f<0x141>(x));
    return x;
}

// ---------------------------------------------------------------------------
// Kernel 1: FPS, one block (512 thr, 8 waves) per batch. Bit-exact fp32
// (no FMA) distance chain; interleaved ownership (pt = j*512 + tid).
// __launch_bounds__(512, 2): LDS already caps at 1 block/CU = 2 waves/EU, so
// raise the VGPR cap to 256 -> px/py/pz (48 regs) + dist (16) stay RESIDENT.
// (Default bounds capped VGPR at 48 -> per-iteration LDS coord reloads were
// the hidden bottleneck across R8-R11.)
// ---------------------------------------------------------------------------
__global__ __launch_bounds__(512, 2) void fps_kernel(const float4* __restrict__ events4,
                                                     int* __restrict__ down_idx,
                                                     float4* __restrict__ out_de) {
    extern __shared__ char smem[];
    float*  rv   = (float*)smem;                   // 8 floats: wave-max partials
    int*    wsl  = (int*)(smem + 32);              // 2 ints: winner slot (parity)
    int*    ssel = (int*)(smem + 64);              // 2048 ints
    float4* spt  = (float4*)(smem + 64 + 4 * M_PTS);

    const int b = blockIdx.x;
    const int tid = threadIdx.x;
    const int wave = tid >> 6;
    const int lane = tid & 63;
    const float4* ev = events4 + (size_t)b * N_PTS;

    for (int i = tid; i < N_PTS; i += 512) spt[i] = ev[i];
    if (tid == 0) { ssel[0] = 0; wsl[0] = 0x7fffffff; wsl[1] = 0x7fffffff; }
    __syncthreads();

    // 16 pts/thread, interleaved: pair pp -> pts (2pp)*512+tid, (2pp+1)*512+tid
    v2f px[8], py[8], pz[8];
    float dist[16];
#pragma unroll
    for (int pp = 0; pp < 8; ++pp) {
        float4 f0 = spt[(2 * pp) * 512 + tid];
        float4 f1 = spt[(2 * pp + 1) * 512 + tid];
        px[pp] = (v2f){f0.x, f1.x};
        py[pp] = (v2f){f0.y, f1.y};
        pz[pp] = (v2f){f0.z, f1.z};
        dist[2 * pp] = 1e10f; dist[2 * pp + 1] = 1e10f;   // reference init
    }

    int last = 0;
    for (int i = 1; i < M_PTS; ++i) {
        float4 L = spt[last];                     // uniform ds_read_b128
        const float nlx = -L.x, nly = -L.y, nlz = -L.z;   // exact sign flips
        const v2f nx2 = (v2f){nlx, nlx};
        const v2f ny2 = (v2f){nly, nly};
        const v2f nz2 = (v2f){nlz, nlz};
#pragma unroll
        for (int pp = 0; pp < 8; ++pp) {
            v2f dx = pk_add(px[pp], nx2);         // == px - lx, exact
            v2f dy = pk_add(py[pp], ny2);
            v2f dz = pk_add(pz[pp], nz2);
            v2f s  = pk_add(pk_add(pk_mul(dx, dx), pk_mul(dy, dy)), pk_mul(dz, dz));
            dist[2 * pp]     = fminf(dist[2 * pp],     s.x);
            dist[2 * pp + 1] = fminf(dist[2 * pp + 1], s.y);
        }
        // per-thread max (tree)
        float t0[8];
#pragma unroll
        for (int j = 0; j < 8; ++j) t0[j] = fmaxf(dist[2 * j], dist[2 * j + 1]);
#pragma unroll
        for (int j = 0; j < 4; ++j) t0[j] = fmaxf(t0[2 * j], t0[2 * j + 1]);
        float bd = fmaxf(fmaxf(t0[0], t0[1]), fmaxf(t0[2], t0[3]));

        // phase A: block max of bd
        float wm = wave_max64(bd);
        if (lane == 63) rv[wave] = wm;
        __syncthreads();                          // B1
        float bm = group8_max(rv[lane & 7]);      // uniform block max

        // phase B: candidates resolve smallest local j, atomicMin global idx
        if (bd == bm) {
            int jm = 0;
#pragma unroll
            for (int j = 15; j >= 0; --j) if (dist[j] == bd) jm = j;
            atomicMin(&wsl[i & 1], jm * 512 + tid);
        }
        __syncthreads();                          // B2
        last = wsl[i & 1];
        if (tid == 0) { ssel[i] = last; wsl[(i + 1) & 1] = 0x7fffffff; }
    }
    __syncthreads();

    for (int i = tid; i < M_PTS; i += 512) {
        int s = ssel[i];
        down_idx[b * M_PTS + i] = s;
        out_de[(size_t)b * M_PTS + i] = spt[s];
    }
}

// ---------------------------------------------------------------------------
// Kernel 2: 16-NN, divergence-free threshold algorithm. (256,1): LDS caps at
// 1 block/CU = 1 wave/EU -> VGPR cap 512, no spills.
// ---------------------------------------------------------------------------
__global__ __launch_bounds__(256, 1) void knn_kernel(const float4* __restrict__ events4,
                                                     const int* __restrict__ down_idx,
                                                     int* __restrict__ knn_idx) {
    extern __shared__ char smem[];
    float2* sxy  = (float2*)smem;                    // 8192 float2 (64 KB)
    float*  sz   = (float*)(smem + N_PTS * 8);       // 8192 floats (32 KB)
    float*  cd   = sz + N_PTS;                       // 32*KCAP floats
    int*    ci   = (int*)(cd + 32 * KCAP);           // 32*KCAP ints
    int*    scnt = (int*)(ci + 32 * KCAP);           // 32 ints

    const int b    = blockIdx.x >> 6;
    const int qg   = blockIdx.x & 63;
    const int tid  = threadIdx.x;
    const int ql   = tid >> 3;
    const int part = tid & 7;

    const float4* ev = events4 + (size_t)b * N_PTS;
    for (int i = tid; i < N_PTS; i += 256) {
        float4 e = ev[i];
        sxy[i] = (float2){e.x, e.y}; sz[i] = e.z;
    }
    if (tid < 32) scnt[tid] = 0;
    __syncthreads();

    const int q  = qg * 32 + ql;
    const int qi = down_idx[b * M_PTS + q];
    const float2 qxy = sxy[qi];
    const float qx = qxy.x, qy = qxy.y, qz = sz[qi];

    float m1 = 1e30f, m2 = 1e30f;
    for (int i = 0; i < N_PTS / 8; ++i) {
        const int p = i * 8 + part;
        float2 pxy = sxy[p];
        float d = sqdist_rn(pxy.x, pxy.y, sz[p], qx, qy, qz);
        float lo = fminf(m1, d);
        m2 = fminf(m2, fmaxf(m1, d));
        m1 = lo;
    }
    const float T = group8_max(m2);

    for (int i = 0; i < N_PTS / 8; ++i) {
        const int p = i * 8 + part;
        float2 pxy = sxy[p];
        float d = sqdist_rn(pxy.x, pxy.y, sz[p], qx, qy, qz);
        if (d <= T) {
            int pos = atomicAdd(&scnt[ql], 1);
            if (pos < KCAP) { cd[ql * KCAP + pos] = d; ci[ql * KCAP + pos] = p; }
        }
    }
    __syncthreads();

    if (part == 0) {
        float nd[16]; int ni[16];
#pragma unroll
        for (int j = 0; j < 16; ++j) { nd[j] = 1e30f; ni[j] = 0x7fffffff; }
        float wmax = 1e30f; int widx = 0x7fffffff; int wslot = 0;
        const int n = scnt[ql];
        const int lim = (n <= KCAP) ? n : 0;
        for (int t = 0; t < lim; ++t) {
            float d = cd[ql * KCAP + t];
            int   p = ci[ql * KCAP + t];
            if (d < wmax || (d == wmax && p < widx)) {
#pragma unroll
                for (int j = 0; j < 16; ++j) if (j == wslot) { nd[j] = d; ni[j] = p; }
                float m_ = -1.0f; int mix_ = -1; int ms_ = 0;
#pragma unroll
                for (int j = 0; j < 16; ++j)
                    if (nd[j] > m_ || (nd[j] == m_ && ni[j] > mix_)) { m_ = nd[j]; mix_ = ni[j]; ms_ = j; }
                wmax = m_; widx = mix_; wslot = ms_;
            }
        }
        if (n > KCAP) {   // exact serial fallback (never expected)
            for (int p = 0; p < N_PTS; ++p) {
                float2 pxy = sxy[p];
                float d = sqdist_rn(pxy.x, pxy.y, sz[p], qx, qy, qz);
                if (d < wmax || (d == wmax && p < widx)) {
#pragma unroll
                    for (int j = 0; j < 16; ++j) if (j == wslot) { nd[j] = d; ni[j] = p; }
                    float m_ = -1.0f; int mix_ = -1; int ms_ = 0;
#pragma unroll
                    for (int j = 0; j < 16; ++j)
                        if (nd[j] > m_ || (nd[j] == m_ && ni[j] > mix_)) { m_ = nd[j]; mix_ = ni[j]; ms_ = j; }
                    wmax = m_; widx = mix_; wslot = ms_;
                }
            }
        }
        int* out = knn_idx + ((size_t)(b * M_PTS + q)) * K_NN;
#pragma unroll
        for (int j = 0; j < 16; ++j) out[j] = ni[j];
    }
}

// ---------------------------------------------------------------------------
// Kernel 3: gather + per-query (16x68)@(68x128) matmul + bias. (256,2):
// VGPR cap 256 keeps w[68] resident; 512 blocks = 2 blocks/CU fits.
// ---------------------------------------------------------------------------
__global__ __launch_bounds__(256, 2) void gmm_kernel(const float4* __restrict__ events4,
                                                     const float4* __restrict__ feat4,
                                                     const float* __restrict__ W,
                                                     const float* __restrict__ bias,
                                                     const int* __restrict__ knn_idx,
                                                     const float4* __restrict__ de4,
                                                     float* __restrict__ hmax_g,
                                                     float* __restrict__ hmin_g,
                                                     float* __restrict__ gsum,
                                                     float* __restrict__ gsq) {
    __shared__ __align__(16) float sg[16 * G_CH];
    __shared__ float scomb[2 * OUT_CH];

    const int b   = blockIdx.x >> 7;
    const int qg  = blockIdx.x & 127;
    const int tid = threadIdx.x;
    const int d   = tid & 127;
    const int kh  = tid >> 7;

    float w[G_CH];
#pragma unroll
    for (int c = 0; c < G_CH; ++c) w[c] = W[c * OUT_CH + d];
    const float breg = bias[d];

    float ssum = 0.f, ssq = 0.f;
    const float4* sg4r = (const float4*)sg;
    float4* sg4w = (float4*)sg;

    for (int qq = 0; qq < 16; ++qq) {
        const int q = qg * 16 + qq;
        const int base = b * M_PTS + q;
        for (int j4 = tid; j4 < 16 * 17; j4 += 256) {
            int k = j4 / 17;
            int c4 = j4 - k * 17;
            int nb = knn_idx[base * K_NN + k];
            float4 v;
            if (c4 == 0) {
                float4 e = events4[(size_t)b * N_PTS + nb];
                float4 d0 = de4[base];
                v = (float4){e.x - d0.x, e.y - d0.y, e.z - d0.z, e.w - d0.w};
            } else {
                v = feat4[((size_t)(b * N_PTS + nb)) * 16 + (c4 - 1)];
            }
            sg4w[j4] = v;
        }
        __syncthreads();

        float hmax = -1e30f, hmin = 1e30f;
#pragma unroll
        for (int k2 = 0; k2 < 8; ++k2) {
            const int k = kh * 8 + k2;
            float acc = breg;
#pragma unroll
            for (int c4 = 0; c4 < 17; ++c4) {
                float4 g = sg4r[k * 17 + c4];
                acc = fmaf(g.x, w[4 * c4 + 0], acc);
                acc = fmaf(g.y, w[4 * c4 + 1], acc);
                acc = fmaf(g.z, w[4 * c4 + 2], acc);
                acc = fmaf(g.w, w[4 * c4 + 3], acc);
            }
            hmax = fmaxf(hmax, acc);
            hmin = fminf(hmin, acc);
            ssum += acc;
            ssq = fmaf(acc, acc, ssq);
        }
        if (kh == 1) { scomb[d] = hmax; scomb[OUT_CH + d] = hmin; }
        __syncthreads();
        if (kh == 0) {
            hmax = fmaxf(hmax, scomb[d]);
            hmin = fminf(hmin, scomb[OUT_CH + d]);
            hmax_g[(size_t)base * OUT_CH + d] = hmax;
            hmin_g[(size_t)base * OUT_CH + d] = hmin;
        }
        __syncthreads();
    }
    if (kh == 1) { scomb[d] = ssum; scomb[OUT_CH + d] = ssq; }
    __syncthreads();
    if (kh == 0) {
        atomicAdd(&gsum[d], ssum + scomb[d]);
        atomicAdd(&gsq[d],  ssq  + scomb[OUT_CH + d]);
    }
}

// ---------------------------------------------------------------------------
// Kernel 4: BN affine + relu + max-over-k via hmax/hmin (affine monotone).
// ---------------------------------------------------------------------------
__global__ __launch_bounds__(256) void fin_kernel(const float* __restrict__ hmax_g,
                                                  const float* __restrict__ hmin_g,
                                                  const float* __restrict__ gsum,
                                                  const float* __restrict__ gsq,
                                                  const float* __restrict__ gamma,
                                                  const float* __restrict__ beta,
                                                  float* __restrict__ out) {
    const size_t e = (size_t)blockIdx.x * 256 + threadIdx.x;
    const int d = (int)(e & 127);
    const float inv_cnt = 1.0f / 131072.0f;
    float mu  = gsum[d] * inv_cnt;
    float var = gsq[d] * inv_cnt - mu * mu;
    float a   = gamma[d] * rsqrtf(var + 1e-5f);
    float sh  = fmaf(-mu, a, beta[d]);
    float hv  = (a >= 0.f) ? hmax_g[e] : hmin_g[e];
    float r   = fmaf(a, hv, sh);
    out[32768 + e] = r > 0.f ? r : 0.f;
}

// ---------------------------------------------------------------------------
extern "C" void kernel_launch(void* const* d_in, const int* in_sizes, int n_in,
                              void* d_out, int out_size, void* d_ws, size_t ws_size,
                              hipStream_t stream) {
    const float* events   = (const float*)d_in[0];
    const float* features = (const float*)d_in[1];
    const float* W        = (const float*)d_in[2];
    const float* bias     = (const float*)d_in[3];
    const float* gamma    = (const float*)d_in[4];
    const float* beta     = (const float*)d_in[5];
    float* out = (float*)d_out;
    char* ws = (char*)d_ws;

    int*   down_idx = (int*)ws;                          // 32768 B
    int*   knn_idx  = (int*)(ws + 32768);                // 524288 B
    float* gsum     = (float*)(ws + 32768 + 524288);     // 512 B
    float* gsq      = gsum + OUT_CH;                     // 512 B
    float* hmaxg    = (float*)(ws + 558080);             // 4 MB
    float* hming    = hmaxg + (size_t)4 * M_PTS * OUT_CH;// 4 MB

    (void)hipMemsetAsync(gsum, 0, 2 * OUT_CH * sizeof(float), stream);

    const size_t fps_lds = 64 + 4 * M_PTS + (size_t)N_PTS * sizeof(float4); // 139328
    fps_kernel<<<4, 512, fps_lds, stream>>>((const float4*)events, down_idx, (float4*)out);

    const size_t knn_lds = (size_t)N_PTS * 8 + (size_t)N_PTS * 4
                         + (size_t)32 * KCAP * 8 + 128;                      // 131200
    knn_kernel<<<256, 256, knn_lds, stream>>>((const float4*)events, down_idx, knn_idx);

    gmm_kernel<<<512, 256, 0, stream>>>((const float4*)events, (const float4*)features,
                                        W, bias, knn_idx, (const float4*)out,
                                        hmaxg, hming, gsum, gsq);

    fin_kernel<<<4096, 256, 0, stream>>>(hmaxg, hming, gsum, gsq, gamma, beta, out);
}

// Round 13
// 2376.099 us; speedup vs baseline: 1.1771x; 1.0166x over previous
//
#include <hip/hip_runtime.h>

#define N_PTS 8192
#define M_PTS 2048
#define K_NN 16
#define IN_CH 64
#define G_CH 68
#define OUT_CH 128
#define KCAP 128

// Unfusable fp32 ops: inline asm cannot be FMA-contracted by the compiler.
__device__ __forceinline__ float subrn(float a, float b) {
    float r; asm("v_sub_f32 %0, %1, %2" : "=v"(r) : "v"(a), "v"(b)); return r;
}
__device__ __forceinline__ float mulrn(float a, float b) {
    float r; asm("v_mul_f32 %0, %1, %2" : "=v"(r) : "v"(a), "v"(b)); return r;
}
__device__ __forceinline__ float addrn(float a, float b) {
    float r; asm("v_add_f32 %0, %1, %2" : "=v"(r) : "v"(a), "v"(b)); return r;
}
// numpy-exact fp32 squared distance: ((dx*dx + dy*dy) + dz*dz), per-op rounding.
__device__ __forceinline__ float sqdist_rn(float ax, float ay, float az,
                                           float bx, float by, float bz) {
    float dx = subrn(ax, bx);
    float dy = subrn(ay, by);
    float dz = subrn(az, bz);
    return addrn(addrn(mulrn(dx, dx), mulrn(dy, dy)), mulrn(dz, dz));
}

// Packed 2xfp32 ops (VOP3P). Each half is a plain IEEE fp32 op -> numerics
// bit-identical to scalar. Subtraction as a + (-b) (exact sign flip).
typedef float v2f __attribute__((ext_vector_type(2)));
__device__ __forceinline__ v2f pk_add(v2f a, v2f b) {
    v2f r; asm("v_pk_add_f32 %0, %1, %2" : "=v"(r) : "v"(a), "v"(b)); return r;
}
__device__ __forceinline__ v2f pk_mul(v2f a, v2f b) {
    v2f r; asm("v_pk_mul_f32 %0, %1, %2" : "=v"(r) : "v"(a), "v"(b)); return r;
}

// ---- DPP helpers ----------------------------------------------------------
template <int CTRL>
__device__ __forceinline__ float movdpp_f(float x) {
    int r = __builtin_amdgcn_mov_dpp(__float_as_int(x), CTRL, 0xf, 0xf, true);
    return __int_as_float(r);
}
// masked bcast stages for wave max: update_dpp old=0 (max with 0 safe, d>=0)
template <int CTRL, int RM>
__device__ __forceinline__ float dppmaxf_m(float x) {
    int r = __builtin_amdgcn_update_dpp(0, __float_as_int(x), CTRL, RM, 0xf, false);
    return fmaxf(x, __int_as_float(r));
}
// full 64-lane max -> valid in lane 63
__device__ __forceinline__ float wave_max64(float x) {
    x = fmaxf(x, movdpp_f<0xB1>(x));   // quad_perm xor1
    x = fmaxf(x, movdpp_f<0x4E>(x));   // quad_perm xor2
    x = fmaxf(x, movdpp_f<0x141>(x));  // row_half_mirror
    x = fmaxf(x, movdpp_f<0x140>(x));  // row_mirror
    x = dppmaxf_m<0x142, 0xa>(x);      // row_bcast15 -> rows 1,3
    x = dppmaxf_m<0x143, 0xc>(x);      // row_bcast31 -> lane63 full
    return x;
}
// 8-lane-group max (lane%8-aligned)
__device__ __forceinline__ float group8_max(float x) {
    x = fmaxf(x, movdpp_f<0xB1>(x));
    x = fmaxf(x, movdpp_f<0x4E>(x));
    x = fmaxf(x, movdpp_f<0x141>(x));
    return x;
}

// ---------------------------------------------------------------------------
// Kernel 1: FPS (unchanged from R12 -- measured at its structural floor:
// serial 2047-iteration chain, 2 barriers + DPP reduce + LDS RTs per iter).
// ---------------------------------------------------------------------------
__global__ __launch_bounds__(512, 2) void fps_kernel(const float4* __restrict__ events4,
                                                     int* __restrict__ down_idx,
                                                     float4* __restrict__ out_de) {
    extern __shared__ char smem[];
    float*  rv   = (float*)smem;                   // 8 floats: wave-max partials
    int*    wsl  = (int*)(smem + 32);              // 2 ints: winner slot (parity)
    int*    ssel = (int*)(smem + 64);              // 2048 ints
    float4* spt  = (float4*)(smem + 64 + 4 * M_PTS);

    const int b = blockIdx.x;
    const int tid = threadIdx.x;
    const int wave = tid >> 6;
    const int lane = tid & 63;
    const float4* ev = events4 + (size_t)b * N_PTS;

    for (int i = tid; i < N_PTS; i += 512) spt[i] = ev[i];
    if (tid == 0) { ssel[0] = 0; wsl[0] = 0x7fffffff; wsl[1] = 0x7fffffff; }
    __syncthreads();

    v2f px[8], py[8], pz[8];
    float dist[16];
#pragma unroll
    for (int pp = 0; pp < 8; ++pp) {
        float4 f0 = spt[(2 * pp) * 512 + tid];
        float4 f1 = spt[(2 * pp + 1) * 512 + tid];
        px[pp] = (v2f){f0.x, f1.x};
        py[pp] = (v2f){f0.y, f1.y};
        pz[pp] = (v2f){f0.z, f1.z};
        dist[2 * pp] = 1e10f; dist[2 * pp + 1] = 1e10f;   // reference init
    }

    int last = 0;
    for (int i = 1; i < M_PTS; ++i) {
        float4 L = spt[last];                     // uniform ds_read_b128
        const float nlx = -L.x, nly = -L.y, nlz = -L.z;   // exact sign flips
        const v2f nx2 = (v2f){nlx, nlx};
        const v2f ny2 = (v2f){nly, nly};
        const v2f nz2 = (v2f){nlz, nlz};
#pragma unroll
        for (int pp = 0; pp < 8; ++pp) {
            v2f dx = pk_add(px[pp], nx2);         // == px - lx, exact
            v2f dy = pk_add(py[pp], ny2);
            v2f dz = pk_add(pz[pp], nz2);
            v2f s  = pk_add(pk_add(pk_mul(dx, dx), pk_mul(dy, dy)), pk_mul(dz, dz));
            dist[2 * pp]     = fminf(dist[2 * pp],     s.x);
            dist[2 * pp + 1] = fminf(dist[2 * pp + 1], s.y);
        }
        float t0[8];
#pragma unroll
        for (int j = 0; j < 8; ++j) t0[j] = fmaxf(dist[2 * j], dist[2 * j + 1]);
#pragma unroll
        for (int j = 0; j < 4; ++j) t0[j] = fmaxf(t0[2 * j], t0[2 * j + 1]);
        float bd = fmaxf(fmaxf(t0[0], t0[1]), fmaxf(t0[2], t0[3]));

        float wm = wave_max64(bd);
        if (lane == 63) rv[wave] = wm;
        __syncthreads();                          // B1
        float bm = group8_max(rv[lane & 7]);      // uniform block max

        if (bd == bm) {
            int jm = 0;
#pragma unroll
            for (int j = 15; j >= 0; --j) if (dist[j] == bd) jm = j;
            atomicMin(&wsl[i & 1], jm * 512 + tid);
        }
        __syncthreads();                          // B2
        last = wsl[i & 1];
        if (tid == 0) { ssel[i] = last; wsl[(i + 1) & 1] = 0x7fffffff; }
    }
    __syncthreads();

    for (int i = tid; i < M_PTS; i += 512) {
        int s = ssel[i];
        down_idx[b * M_PTS + i] = s;
        out_de[(size_t)b * M_PTS + i] = spt[s];
    }
}

// ---------------------------------------------------------------------------
// Kernel 2: 16-NN, threshold algorithm. Scan repartitioned to ADJACENT point
// pairs (p = i*16 + part*2): one ds_read_b128 (xy of 2 pts) + one b64 (z of
// 2 pts) per pair -- half the LDS ops of the per-point scan. T bound valid
// for any partition (union of per-lane top-2 = 16 pts <= T); candidate set
// {d <= T} partition-independent; final top-16 exact lexicographic.
// ---------------------------------------------------------------------------
__global__ __launch_bounds__(256, 1) void knn_kernel(const float4* __restrict__ events4,
                                                     const int* __restrict__ down_idx,
                                                     int* __restrict__ knn_idx) {
    extern __shared__ char smem[];
    float2* sxy  = (float2*)smem;                    // 8192 float2 (64 KB)
    float*  sz   = (float*)(smem + N_PTS * 8);       // 8192 floats (32 KB)
    float*  cd   = sz + N_PTS;                       // 32*KCAP floats
    int*    ci   = (int*)(cd + 32 * KCAP);           // 32*KCAP ints
    int*    scnt = (int*)(ci + 32 * KCAP);           // 32 ints

    const int b    = blockIdx.x >> 6;
    const int qg   = blockIdx.x & 63;
    const int tid  = threadIdx.x;
    const int ql   = tid >> 3;
    const int part = tid & 7;

    const float4* ev = events4 + (size_t)b * N_PTS;
    for (int i = tid; i < N_PTS; i += 256) {
        float4 e = ev[i];
        sxy[i] = (float2){e.x, e.y}; sz[i] = e.z;
    }
    if (tid < 32) scnt[tid] = 0;
    __syncthreads();

    const int q  = qg * 32 + ql;
    const int qi = down_idx[b * M_PTS + q];
    const float2 qxy = sxy[qi];
    const float qx = qxy.x, qy = qxy.y, qz = sz[qi];

    const float4* sxy4 = (const float4*)sxy;
    const float2* sz2  = (const float2*)sz;

    // pass 1: branchless top-2 smallest per lane, 2 adjacent pts per iter
    float m1 = 1e30f, m2 = 1e30f;
    for (int i = 0; i < N_PTS / 16; ++i) {
        const int ph = i * 8 + part;              // pair index; pts 2ph, 2ph+1
        float4 xy = sxy4[ph];
        float2 zz = sz2[ph];
        float d0 = sqdist_rn(xy.x, xy.y, zz.x, qx, qy, qz);
        float d1 = sqdist_rn(xy.z, xy.w, zz.y, qx, qy, qz);
        float lo0 = fminf(m1, d0);
        m2 = fminf(m2, fmaxf(m1, d0));
        m1 = lo0;
        float lo1 = fminf(m1, d1);
        m2 = fminf(m2, fmaxf(m1, d1));
        m1 = lo1;
    }
    const float T = group8_max(m2);

    // pass 2: compact candidates (same paired reads)
    for (int i = 0; i < N_PTS / 16; ++i) {
        const int ph = i * 8 + part;
        float4 xy = sxy4[ph];
        float2 zz = sz2[ph];
        float d0 = sqdist_rn(xy.x, xy.y, zz.x, qx, qy, qz);
        float d1 = sqdist_rn(xy.z, xy.w, zz.y, qx, qy, qz);
        if (d0 <= T) {
            int pos = atomicAdd(&scnt[ql], 1);
            if (pos < KCAP) { cd[ql * KCAP + pos] = d0; ci[ql * KCAP + pos] = 2 * ph; }
        }
        if (d1 <= T) {
            int pos = atomicAdd(&scnt[ql], 1);
            if (pos < KCAP) { cd[ql * KCAP + pos] = d1; ci[ql * KCAP + pos] = 2 * ph + 1; }
        }
    }
    __syncthreads();

    if (part == 0) {
        float nd[16]; int ni[16];
#pragma unroll
        for (int j = 0; j < 16; ++j) { nd[j] = 1e30f; ni[j] = 0x7fffffff; }
        float wmax = 1e30f; int widx = 0x7fffffff; int wslot = 0;
        const int n = scnt[ql];
        const int lim = (n <= KCAP) ? n : 0;
        for (int t = 0; t < lim; ++t) {
            float d = cd[ql * KCAP + t];
            int   p = ci[ql * KCAP + t];
            if (d < wmax || (d == wmax && p < widx)) {
#pragma unroll
                for (int j = 0; j < 16; ++j) if (j == wslot) { nd[j] = d; ni[j] = p; }
                float m_ = -1.0f; int mix_ = -1; int ms_ = 0;
#pragma unroll
                for (int j = 0; j < 16; ++j)
                    if (nd[j] > m_ || (nd[j] == m_ && ni[j] > mix_)) { m_ = nd[j]; mix_ = ni[j]; ms_ = j; }
                wmax = m_; widx = mix_; wslot = ms_;
            }
        }
        if (n > KCAP) {   // exact serial fallback (never expected)
            for (int p = 0; p < N_PTS; ++p) {
                float2 pxy = sxy[p];
                float d = sqdist_rn(pxy.x, pxy.y, sz[p], qx, qy, qz);
                if (d < wmax || (d == wmax && p < widx)) {
#pragma unroll
                    for (int j = 0; j < 16; ++j) if (j == wslot) { nd[j] = d; ni[j] = p; }
                    float m_ = -1.0f; int mix_ = -1; int ms_ = 0;
#pragma unroll
                    for (int j = 0; j < 16; ++j)
                        if (nd[j] > m_ || (nd[j] == m_ && ni[j] > mix_)) { m_ = nd[j]; mix_ = ni[j]; ms_ = j; }
                    wmax = m_; widx = mix_; wslot = ms_;
                }
            }
        }
        int* out = knn_idx + ((size_t)(b * M_PTS + q)) * K_NN;
#pragma unroll
        for (int j = 0; j < 16; ++j) out[j] = ni[j];
    }
}

// ---------------------------------------------------------------------------
// Kernel 3: gather + per-query (16x68)@(68x128) matmul + bias. Restructured:
// thread = (d, query-slot qs), computes ALL 16 k's for its query -> no kh
// hmax/hmin exchange; 2 queries staged per round -> 2 barriers per 2 queries
// (was ~3 per query). 512 blocks x 256 thr, 16 queries/block.
// ---------------------------------------------------------------------------
__global__ __launch_bounds__(256, 2) void gmm_kernel(const float4* __restrict__ events4,
                                                     const float4* __restrict__ feat4,
                                                     const float* __restrict__ W,
                                                     const float* __restrict__ bias,
                                                     const int* __restrict__ knn_idx,
                                                     const float4* __restrict__ de4,
                                                     float* __restrict__ hmax_g,
                                                     float* __restrict__ hmin_g,
                                                     float* __restrict__ gsum,
                                                     float* __restrict__ gsq) {
    __shared__ __align__(16) float4 sg4[2 * 16 * 17];   // 2 queries x 16 k x 17
    __shared__ float scomb[2 * OUT_CH];

    const int b   = blockIdx.x >> 7;
    const int qg  = blockIdx.x & 127;
    const int tid = threadIdx.x;
    const int d   = tid & 127;
    const int qs  = tid >> 7;          // query slot 0/1

    float w[G_CH];
#pragma unroll
    for (int c = 0; c < G_CH; ++c) w[c] = W[c * OUT_CH + d];
    const float breg = bias[d];

    float ssum = 0.f, ssq = 0.f;

    for (int r = 0; r < 8; ++r) {
        const int base = b * M_PTS + qg * 16 + 2 * r;
        // stage 2 queries: 544 float4 chunks
        for (int j4 = tid; j4 < 2 * 16 * 17; j4 += 256) {
            int qq = j4 / 272;
            int rem = j4 - qq * 272;
            int k = rem / 17;
            int c4 = rem - k * 17;
            int nb = knn_idx[(base + qq) * K_NN + k];
            float4 v;
            if (c4 == 0) {
                float4 e = events4[(size_t)b * N_PTS + nb];
                float4 d0 = de4[base + qq];
                v = (float4){e.x - d0.x, e.y - d0.y, e.z - d0.z, e.w - d0.w};
            } else {
                v = feat4[((size_t)(b * N_PTS + nb)) * 16 + (c4 - 1)];
            }
            sg4[j4] = v;
        }
        __syncthreads();

        // compute: this thread does all 16 k's of query (base + qs), column d
        float hmax = -1e30f, hmin = 1e30f;
#pragma unroll
        for (int k = 0; k < 16; ++k) {
            float acc = breg;
#pragma unroll
            for (int c4 = 0; c4 < 17; ++c4) {
                float4 g = sg4[qs * 272 + k * 17 + c4];
                acc = fmaf(g.x, w[4 * c4 + 0], acc);
                acc = fmaf(g.y, w[4 * c4 + 1], acc);
                acc = fmaf(g.z, w[4 * c4 + 2], acc);
                acc = fmaf(g.w, w[4 * c4 + 3], acc);
            }
            hmax = fmaxf(hmax, acc);
            hmin = fminf(hmin, acc);
            ssum += acc;
            ssq = fmaf(acc, acc, ssq);
        }
        const size_t o = (size_t)(base + qs) * OUT_CH + d;
        hmax_g[o] = hmax;
        hmin_g[o] = hmin;
        __syncthreads();   // protect sg before next staging
    }

    if (qs == 1) { scomb[d] = ssum; scomb[OUT_CH + d] = ssq; }
    __syncthreads();
    if (qs == 0) {
        atomicAdd(&gsum[d], ssum + scomb[d]);
        atomicAdd(&gsq[d],  ssq  + scomb[OUT_CH + d]);
    }
}

// ---------------------------------------------------------------------------
// Kernel 4: BN affine + relu + max-over-k via hmax/hmin (affine monotone).
// ---------------------------------------------------------------------------
__global__ __launch_bounds__(256) void fin_kernel(const float* __restrict__ hmax_g,
                                                  const float* __restrict__ hmin_g,
                                                  const float* __restrict__ gsum,
                                                  const float* __restrict__ gsq,
                                                  const float* __restrict__ gamma,
                                                  const float* __restrict__ beta,
                                                  float* __restrict__ out) {
    const size_t e = (size_t)blockIdx.x * 256 + threadIdx.x;
    const int d = (int)(e & 127);
    const float inv_cnt = 1.0f / 131072.0f;
    float mu  = gsum[d] * inv_cnt;
    float var = gsq[d] * inv_cnt - mu * mu;
    float a   = gamma[d] * rsqrtf(var + 1e-5f);
    float sh  = fmaf(-mu, a, beta[d]);
    float hv  = (a >= 0.f) ? hmax_g[e] : hmin_g[e];
    float r   = fmaf(a, hv, sh);
    out[32768 + e] = r > 0.f ? r : 0.f;
}

// ---------------------------------------------------------------------------
extern "C" void kernel_launch(void* const* d_in, const int* in_sizes, int n_in,
                              void* d_out, int out_size, void* d_ws, size_t ws_size,
                              hipStream_t stream) {
    const float* events   = (const float*)d_in[0];
    const float* features = (const float*)d_in[1];
    const float* W        = (const float*)d_in[2];
    const float* bias     = (const float*)d_in[3];
    const float* gamma    = (const float*)d_in[4];
    const float* beta     = (const float*)d_in[5];
    float* out = (float*)d_out;
    char* ws = (char*)d_ws;

    int*   down_idx = (int*)ws;                          // 32768 B
    int*   knn_idx  = (int*)(ws + 32768);                // 524288 B
    float* gsum     = (float*)(ws + 32768 + 524288);     // 512 B
    float* gsq      = gsum + OUT_CH;                     // 512 B
    float* hmaxg    = (float*)(ws + 558080);             // 4 MB
    float* hming    = hmaxg + (size_t)4 * M_PTS * OUT_CH;// 4 MB

    (void)hipMemsetAsync(gsum, 0, 2 * OUT_CH * sizeof(float), stream);

    const size_t fps_lds = 64 + 4 * M_PTS + (size_t)N_PTS * sizeof(float4); // 139328
    fps_kernel<<<4, 512, fps_lds, stream>>>((const float4*)events, down_idx, (float4*)out);

    const size_t knn_lds = (size_t)N_PTS * 8 + (size_t)N_PTS * 4
                         + (size_t)32 * KCAP * 8 + 128;                      // 131200
    knn_kernel<<<256, 256, knn_lds, stream>>>((const float4*)events, down_idx, knn_idx);

    gmm_kernel<<<512, 256, 0, stream>>>((const float4*)events, (const float4*)features,
                                        W, bias, knn_idx, (const float4*)out,
                                        hmaxg, hming, gsum, gsq);

    fin_kernel<<<4096, 256, 0, stream>>>(hmaxg, hming, gsum, gsq, gamma, beta, out);
}